// Round 2
// baseline (737.191 us; speedup 1.0000x reference)
//
#include <hip/hip_runtime.h>
#include <hip/hip_bf16.h>
#include <math.h>

#define Bc 4
#define Sc 2048
#define Dc 1024
#define Hc 16
#define DKc 64
#define DFFc 4096
#define Mc (Bc*Sc)
#define LN_EPS 1e-6f

typedef unsigned short ushort_t;
typedef short bf16x8 __attribute__((ext_vector_type(8)));
typedef float f32x4 __attribute__((ext_vector_type(4)));

typedef __attribute__((address_space(3))) void lds_void_t;
typedef __attribute__((address_space(1))) const void gconst_void_t;

__device__ __forceinline__ void gload_lds16(const void* g, void* l) {
  __builtin_amdgcn_global_load_lds((gconst_void_t*)g, (lds_void_t*)l, 16, 0, 0);
}

__device__ __forceinline__ ushort_t f2bf(float f) {
  union { float f; unsigned int u; } a; a.f = f;
  unsigned int r = a.u + 0x7fffu + ((a.u >> 16) & 1u);
  return (ushort_t)(r >> 16);
}

// ---------------- weight transpose + f32->bf16 convert ----------------
// W: [K,N] f32 row-major  ->  WT: [N,K] bf16 row-major
__global__ __launch_bounds__(256) void k_transpose_cvt(
    const float* __restrict__ W, ushort_t* __restrict__ WT, int K, int N) {
  __shared__ float t[32][33];
  const int tx = threadIdx.x & 31, ty = threadIdx.x >> 5;  // ty 0..7
  const int n0 = blockIdx.x * 32, k0 = blockIdx.y * 32;
#pragma unroll
  for (int i = 0; i < 4; ++i)
    t[ty + i * 8][tx] = W[(size_t)(k0 + ty + i * 8) * N + n0 + tx];
  __syncthreads();
#pragma unroll
  for (int i = 0; i < 4; ++i)
    WT[(size_t)(n0 + ty + i * 8) * K + k0 + tx] = f2bf(t[tx][ty + i * 8]);
}

// ---------------- layernorm (f32 in -> bf16 out), ddof=1, /(std+eps) ----------------
__global__ __launch_bounds__(256) void k_layernorm(
    const float* __restrict__ x, const float* __restrict__ alpha,
    const float* __restrict__ beta, ushort_t* __restrict__ out) {
  const int row = blockIdx.x;
  const int tid = threadIdx.x;
  const int w = tid >> 6, lane = tid & 63;
  const float4 v = ((const float4*)(x + (size_t)row * Dc))[tid];
  float s = v.x + v.y + v.z + v.w;
#pragma unroll
  for (int m = 32; m >= 1; m >>= 1) s += __shfl_xor(s, m, 64);
  __shared__ float ws[8];
  if (lane == 0) ws[w] = s;
  __syncthreads();
  s = ws[0] + ws[1] + ws[2] + ws[3];
  const float mean = s * (1.0f / Dc);
  const float dx = v.x - mean, dy = v.y - mean, dz = v.z - mean, dw = v.w - mean;
  float ss = dx * dx + dy * dy + dz * dz + dw * dw;
#pragma unroll
  for (int m = 32; m >= 1; m >>= 1) ss += __shfl_xor(ss, m, 64);
  if (lane == 0) ws[4 + w] = ss;
  __syncthreads();
  ss = ws[4] + ws[5] + ws[6] + ws[7];
  const float stdv = sqrtf(ss / (float)(Dc - 1));
  const float inv = 1.0f / (stdv + LN_EPS);
  const float4 a = ((const float4*)alpha)[tid];
  const float4 b = ((const float4*)beta)[tid];
  ushort4 o;
  o.x = f2bf(a.x * dx * inv + b.x);
  o.y = f2bf(a.y * dy * inv + b.y);
  o.z = f2bf(a.z * dz * inv + b.z);
  o.w = f2bf(a.w * dw * inv + b.w);
  *(ushort4*)(out + (size_t)row * Dc + tid * 4) = o;
}

// ---------------- bf16 GEMM, m97 structure: 128x128 tile, BK=32, 4 waves ----------------
// A: [M,K] bf16 row-major.  BT: [N,K] bf16 row-major.  C = A*B + bias (+resid)
// MODE 0: bf16 out.  MODE 1: f32 out with +resid.  MODE 2: gelu -> bf16 out.
// MODE 3: bf16 out TRANSPOSED to [B,H,DK,S] (for the V projection).
template <int MODE>
__global__ __launch_bounds__(256) void k_gemm(
    const ushort_t* __restrict__ A, const ushort_t* __restrict__ BT,
    const float* __restrict__ bias, const float* __restrict__ resid,
    void* __restrict__ Cout, int N, int K) {
  __shared__ __align__(16) ushort_t As[128 * 32];
  __shared__ __align__(16) ushort_t Bs[128 * 32];
  const int tid = threadIdx.x;
  const int lane = tid & 63;
  const int w = tid >> 6, wm = w >> 1, wn = w & 1;
  const int lrow = lane & 15, lgrp = lane >> 4;
  const int m0 = blockIdx.y << 7, n0 = blockIdx.x << 7;

  const f32x4 zero4 = {0.f, 0.f, 0.f, 0.f};
  f32x4 acc[4][4];
#pragma unroll
  for (int i = 0; i < 4; ++i)
#pragma unroll
    for (int j = 0; j < 4; ++j) acc[i][j] = zero4;

  const int c0 = tid, c1 = tid + 256;  // 16B chunks, 512 per 128x32 tile
  const ushort_t* Ag0 = A + (size_t)(m0 + (c0 >> 2)) * K + (c0 & 3) * 8;
  const ushort_t* Ag1 = A + (size_t)(m0 + (c1 >> 2)) * K + (c1 & 3) * 8;
  const ushort_t* Bg0 = BT + (size_t)(n0 + (c0 >> 2)) * K + (c0 & 3) * 8;
  const ushort_t* Bg1 = BT + (size_t)(n0 + (c1 >> 2)) * K + (c1 & 3) * 8;
  ushort_t* Al0 = As + c0 * 8;
  ushort_t* Al1 = As + c1 * 8;
  ushort_t* Bl0 = Bs + c0 * 8;
  ushort_t* Bl1 = Bs + c1 * 8;

  int aoff[4], boff[4];
#pragma unroll
  for (int m = 0; m < 4; ++m) aoff[m] = (wm * 64 + m * 16 + lrow) * 32 + lgrp * 8;
#pragma unroll
  for (int n = 0; n < 4; ++n) boff[n] = (wn * 64 + n * 16 + lrow) * 32 + lgrp * 8;

  for (int kk = 0; kk < K; kk += 32) {
    gload_lds16(Ag0 + kk, Al0);
    gload_lds16(Ag1 + kk, Al1);
    gload_lds16(Bg0 + kk, Bl0);
    gload_lds16(Bg1 + kk, Bl1);
    __syncthreads();  // drains vmcnt -> tile resident
    bf16x8 a[4], b[4];
#pragma unroll
    for (int m = 0; m < 4; ++m) a[m] = *(const bf16x8*)(As + aoff[m]);
#pragma unroll
    for (int n = 0; n < 4; ++n) b[n] = *(const bf16x8*)(Bs + boff[n]);
#pragma unroll
    for (int m = 0; m < 4; ++m)
#pragma unroll
      for (int n = 0; n < 4; ++n)
        acc[m][n] = __builtin_amdgcn_mfma_f32_16x16x32_bf16(a[m], b[n], acc[m][n], 0, 0, 0);
    __syncthreads();  // readers done before next stage overwrites
  }

  float bv[4];
#pragma unroll
  for (int n = 0; n < 4; ++n) bv[n] = bias[n0 + wn * 64 + n * 16 + lrow];
#pragma unroll
  for (int m = 0; m < 4; ++m)
#pragma unroll
    for (int n = 0; n < 4; ++n) {
      if (MODE == 3) {
        // rows m0+wm*64+m*16+lgrp*4 + r (r=0..3) are s-consecutive; col = h*64+d
        const size_t s0 = (size_t)(m0 + wm * 64 + m * 16 + lgrp * 4);
        const int gb = (int)(s0 >> 11);          // batch
        const int ss = (int)(s0 & 2047);         // seq pos (mult of 4)
        const int col = n0 + wn * 64 + n * 16 + lrow;
        const int hh = col >> 6, dd = col & 63;
        ushort4 o4;
        o4.x = f2bf(acc[m][n][0] + bv[n]);
        o4.y = f2bf(acc[m][n][1] + bv[n]);
        o4.z = f2bf(acc[m][n][2] + bv[n]);
        o4.w = f2bf(acc[m][n][3] + bv[n]);
        ushort_t* dst = (ushort_t*)Cout + ((size_t)(gb * Hc + hh) * DKc + dd) * Sc + ss;
        *(ushort4*)dst = o4;
      } else {
#pragma unroll
        for (int r = 0; r < 4; ++r) {
          const size_t row = (size_t)(m0 + wm * 64 + m * 16 + lgrp * 4 + r);
          const size_t col = (size_t)(n0 + wn * 64 + n * 16 + lrow);
          float v = acc[m][n][r] + bv[n];
          if (MODE == 2) v = 0.5f * v * (1.0f + erff(v * 0.70710678118654752f));
          if (MODE == 1) {
            v += resid[row * N + col];
            ((float*)Cout)[row * N + col] = v;
          } else {
            ((ushort_t*)Cout)[row * N + col] = f2bf(v);
          }
        }
      }
    }
}

// ---------------- flash attention v2: 128 q-rows/block, 4 waves x 32 rows ----------------
// Q,K: [B,S,H*DK] bf16.  Vt: [B,H,DK,S] bf16 (pre-transposed).  O: [B,S,H*DK] bf16.
// No __syncthreads in the K-loop: the only LDS (Pl) is per-wave.
__global__ __launch_bounds__(256) void k_attn2(
    const ushort_t* __restrict__ Qb, const ushort_t* __restrict__ Kb,
    const ushort_t* __restrict__ Vt, const int* __restrict__ mask,
    ushort_t* __restrict__ Ob) {
  const int bh = blockIdx.y;
  const int b = bh >> 4, h = bh & 15;
  const int qb = blockIdx.x * 128;
  const int tid = threadIdx.x;
  const int lane = tid & 63, w = tid >> 6;
  const int lrow = lane & 15, lgrp = lane >> 4;
  const size_t bS = (size_t)b * Sc;

  __shared__ __align__(16) ushort_t Pl[4][16][74];  // per-wave P tile (stride 37 dw)

  const f32x4 zero4 = {0.f, 0.f, 0.f, 0.f};
  const int qrow0 = qb + w * 32;

  // Q fragments (A-operand): row = lrow, k = lgrp*8+j; two 16-row sub-tiles
  bf16x8 qf[2][2];
#pragma unroll
  for (int s = 0; s < 2; ++s) {
    const ushort_t* qp = Qb + (bS + qrow0 + s * 16 + lrow) * Dc + h * DKc;
    qf[s][0] = *(const bf16x8*)(qp + lgrp * 8);
    qf[s][1] = *(const bf16x8*)(qp + 32 + lgrp * 8);
  }

  f32x4 acc[2][4];
  float rowm[2][4], rowl[2][4];
#pragma unroll
  for (int s = 0; s < 2; ++s)
#pragma unroll
    for (int n = 0; n < 4; ++n) acc[s][n] = zero4;
#pragma unroll
  for (int s = 0; s < 2; ++s)
#pragma unroll
    for (int r = 0; r < 4; ++r) { rowm[s][r] = -INFINITY; rowl[s][r] = 0.f; }

  const ushort_t* Vth = Vt + (size_t)bh * DKc * Sc;

  for (int kv = 0; kv < Sc; kv += 64) {
    int mv[4];
#pragma unroll
    for (int n = 0; n < 4; ++n) mv[n] = mask[bS + kv + n * 16 + lrow];
    // K fragments shared across both q sub-tiles
    bf16x8 kf[4][2];
#pragma unroll
    for (int n = 0; n < 4; ++n) {
      const ushort_t* kp = Kb + (bS + kv + n * 16 + lrow) * Dc + h * DKc;
      kf[n][0] = *(const bf16x8*)(kp + lgrp * 8);
      kf[n][1] = *(const bf16x8*)(kp + 32 + lgrp * 8);
    }
#pragma unroll
    for (int s = 0; s < 2; ++s) {
      // QK^T: S-tile [16q][64k]
      f32x4 sc[4];
#pragma unroll
      for (int n = 0; n < 4; ++n) {
        sc[n] = zero4;
        sc[n] = __builtin_amdgcn_mfma_f32_16x16x32_bf16(qf[s][0], kf[n][0], sc[n], 0, 0, 0);
        sc[n] = __builtin_amdgcn_mfma_f32_16x16x32_bf16(qf[s][1], kf[n][1], sc[n], 0, 0, 0);
      }
      // online softmax, wave-parallel (rows live in 16-lane groups)
      float sv[4][4];
#pragma unroll
      for (int n = 0; n < 4; ++n)
#pragma unroll
        for (int r = 0; r < 4; ++r)
          sv[n][r] = (mv[n] != 0) ? sc[n][r] * 0.125f : -1e9f;
      float pm[4];
#pragma unroll
      for (int r = 0; r < 4; ++r) {
        pm[r] = fmaxf(fmaxf(sv[0][r], sv[1][r]), fmaxf(sv[2][r], sv[3][r]));
#pragma unroll
        for (int mm = 8; mm >= 1; mm >>= 1) pm[r] = fmaxf(pm[r], __shfl_xor(pm[r], mm, 16));
      }
      float scl[4];
#pragma unroll
      for (int r = 0; r < 4; ++r) {
        const float mn = fmaxf(rowm[s][r], pm[r]);
        scl[r] = __expf(rowm[s][r] - mn);
        rowm[s][r] = mn;
      }
      float p[4][4], ps[4];
#pragma unroll
      for (int r = 0; r < 4; ++r) ps[r] = 0.f;
#pragma unroll
      for (int n = 0; n < 4; ++n)
#pragma unroll
        for (int r = 0; r < 4; ++r) {
          p[n][r] = __expf(sv[n][r] - rowm[s][r]);
          ps[r] += p[n][r];
        }
#pragma unroll
      for (int r = 0; r < 4; ++r) {
#pragma unroll
        for (int mm = 8; mm >= 1; mm >>= 1) ps[r] += __shfl_xor(ps[r], mm, 16);
        rowl[s][r] = rowl[s][r] * scl[r] + ps[r];
      }
#pragma unroll
      for (int n = 0; n < 4; ++n)
#pragma unroll
        for (int r = 0; r < 4; ++r) acc[s][n][r] *= scl[r];
      // P (D-layout) -> per-wave LDS so it can be re-read as PV's A-operand
#pragma unroll
      for (int n = 0; n < 4; ++n)
#pragma unroll
        for (int r = 0; r < 4; ++r)
          Pl[w][lgrp * 4 + r][n * 16 + lrow] = f2bf(p[n][r]);
      // PV: acc += P * V   (B-fragments straight from pre-transposed Vt rows)
      const bf16x8 pa0 = *(const bf16x8*)(&Pl[w][lrow][lgrp * 8]);
      const bf16x8 pa1 = *(const bf16x8*)(&Pl[w][lrow][32 + lgrp * 8]);
#pragma unroll
      for (int n2 = 0; n2 < 4; ++n2) {
        const ushort_t* vp = Vth + (size_t)(n2 * 16 + lrow) * Sc + kv;
        const bf16x8 vb0 = *(const bf16x8*)(vp + lgrp * 8);
        const bf16x8 vb1 = *(const bf16x8*)(vp + 32 + lgrp * 8);
        acc[s][n2] = __builtin_amdgcn_mfma_f32_16x16x32_bf16(pa0, vb0, acc[s][n2], 0, 0, 0);
        acc[s][n2] = __builtin_amdgcn_mfma_f32_16x16x32_bf16(pa1, vb1, acc[s][n2], 0, 0, 0);
      }
    }
  }
  // epilogue
#pragma unroll
  for (int s = 0; s < 2; ++s)
#pragma unroll
    for (int n2 = 0; n2 < 4; ++n2)
#pragma unroll
      for (int r = 0; r < 4; ++r) {
        const int qrow = qrow0 + s * 16 + lgrp * 4 + r;
        const float o = acc[s][n2][r] / rowl[s][r];
        Ob[(bS + qrow) * Dc + h * DKc + n2 * 16 + lrow] = f2bf(o);
      }
}

// ---------------- launcher ----------------
extern "C" void kernel_launch(void* const* d_in, const int* in_sizes, int n_in,
                              void* d_out, int out_size, void* d_ws, size_t ws_size,
                              hipStream_t stream) {
  const float* x     = (const float*)d_in[0];
  const int* mask    = (const int*)d_in[1];
  const float* wq_w  = (const float*)d_in[2];
  const float* wq_b  = (const float*)d_in[3];
  const float* wk_w  = (const float*)d_in[4];
  const float* wk_b  = (const float*)d_in[5];
  const float* wv_w  = (const float*)d_in[6];
  const float* wv_b  = (const float*)d_in[7];
  const float* wo_w  = (const float*)d_in[8];
  const float* wo_b  = (const float*)d_in[9];
  const float* ff_w0 = (const float*)d_in[10];
  const float* ff_b0 = (const float*)d_in[11];
  const float* ff_w1 = (const float*)d_in[12];
  const float* ff_b1 = (const float*)d_in[13];
  const float* ln0_a = (const float*)d_in[14];
  const float* ln0_b = (const float*)d_in[15];
  const float* ln1_a = (const float*)d_in[16];
  const float* ln1_b = (const float*)d_in[17];
  float* out = (float*)d_out;

  char* ws = (char*)d_ws;
  size_t off = 0;
  ushort_t* WTq = (ushort_t*)(ws + off); off += (size_t)Dc * Dc * 2;
  ushort_t* WTk = (ushort_t*)(ws + off); off += (size_t)Dc * Dc * 2;
  ushort_t* WTv = (ushort_t*)(ws + off); off += (size_t)Dc * Dc * 2;
  ushort_t* WTo = (ushort_t*)(ws + off); off += (size_t)Dc * Dc * 2;
  ushort_t* WT0 = (ushort_t*)(ws + off); off += (size_t)DFFc * Dc * 2;  // [4096,1024]
  ushort_t* WT1 = (ushort_t*)(ws + off); off += (size_t)Dc * DFFc * 2;  // [1024,4096]
  ushort_t* hbuf = (ushort_t*)(ws + off); off += (size_t)Mc * Dc * 2;
  ushort_t* qbuf = (ushort_t*)(ws + off); off += (size_t)Mc * Dc * 2;
  ushort_t* kbuf = (ushort_t*)(ws + off); off += (size_t)Mc * Dc * 2;
  ushort_t* vtb  = (ushort_t*)(ws + off); off += (size_t)Mc * Dc * 2;  // Vt [B,H,DK,S]
  ushort_t* abuf = (ushort_t*)(ws + off); off += (size_t)Mc * Dc * 2;
  ushort_t* gbuf = qbuf;  // [8192,4096] overlays dead q/k/vt/attn buffers (64MB)

  const dim3 blk(256);
  // weight prep
  k_transpose_cvt<<<dim3(Dc / 32, Dc / 32), blk, 0, stream>>>(wq_w, WTq, Dc, Dc);
  k_transpose_cvt<<<dim3(Dc / 32, Dc / 32), blk, 0, stream>>>(wk_w, WTk, Dc, Dc);
  k_transpose_cvt<<<dim3(Dc / 32, Dc / 32), blk, 0, stream>>>(wv_w, WTv, Dc, Dc);
  k_transpose_cvt<<<dim3(Dc / 32, Dc / 32), blk, 0, stream>>>(wo_w, WTo, Dc, Dc);
  k_transpose_cvt<<<dim3(DFFc / 32, Dc / 32), blk, 0, stream>>>(ff_w0, WT0, Dc, DFFc);
  k_transpose_cvt<<<dim3(Dc / 32, DFFc / 32), blk, 0, stream>>>(ff_w1, WT1, DFFc, Dc);
  // LN0
  k_layernorm<<<Mc, blk, 0, stream>>>(x, ln0_a, ln0_b, hbuf);
  // Q,K projections; V projection writes pre-transposed [B,H,DK,S]
  k_gemm<0><<<dim3(Dc / 128, Mc / 128), blk, 0, stream>>>(hbuf, WTq, wq_b, nullptr, qbuf, Dc, Dc);
  k_gemm<0><<<dim3(Dc / 128, Mc / 128), blk, 0, stream>>>(hbuf, WTk, wk_b, nullptr, kbuf, Dc, Dc);
  k_gemm<3><<<dim3(Dc / 128, Mc / 128), blk, 0, stream>>>(hbuf, WTv, wv_b, nullptr, vtb, Dc, Dc);
  // attention
  k_attn2<<<dim3(Sc / 128, Bc * Hc), blk, 0, stream>>>(qbuf, kbuf, vtb, mask, abuf);
  // O projection + residual(x) -> d_out (f32)
  k_gemm<1><<<dim3(Dc / 128, Mc / 128), blk, 0, stream>>>(abuf, WTo, wo_b, x, out, Dc, Dc);
  // LN1
  k_layernorm<<<Mc, blk, 0, stream>>>(out, ln1_a, ln1_b, hbuf);
  // FFN0 + exact gelu -> gbuf (bf16)
  k_gemm<2><<<dim3(DFFc / 128, Mc / 128), blk, 0, stream>>>(hbuf, WT0, ff_b0, nullptr, gbuf, DFFc, Dc);
  // FFN1 + residual(d_out) -> d_out (f32), in-place safe (1 thread per element)
  k_gemm<1><<<dim3(Dc / 128, Mc / 128), blk, 0, stream>>>(gbuf, WT1, ff_b1, out, out, Dc, DFFc);
}

// Round 3
// 683.293 us; speedup vs baseline: 1.0789x; 1.0789x over previous
//
#include <hip/hip_runtime.h>
#include <hip/hip_bf16.h>
#include <math.h>

#define Bc 4
#define Sc 2048
#define Dc 1024
#define Hc 16
#define DKc 64
#define DFFc 4096
#define Mc (Bc*Sc)
#define LN_EPS 1e-6f

typedef unsigned short ushort_t;
typedef short bf16x8 __attribute__((ext_vector_type(8)));
typedef float f32x4 __attribute__((ext_vector_type(4)));
typedef float f32x16 __attribute__((ext_vector_type(16)));

typedef __attribute__((address_space(3))) void lds_void_t;
typedef __attribute__((address_space(1))) const void gconst_void_t;

__device__ __forceinline__ void gload_lds16(const void* g, void* l) {
  __builtin_amdgcn_global_load_lds((gconst_void_t*)g, (lds_void_t*)l, 16, 0, 0);
}

__device__ __forceinline__ ushort_t f2bf(float f) {
  union { float f; unsigned int u; } a; a.f = f;
  unsigned int r = a.u + 0x7fffu + ((a.u >> 16) & 1u);
  return (ushort_t)(r >> 16);
}

// v_permlane32_swap_b32: a[32:63] <-> b[0:31].
// lane<32: a'=own, b'=partner(lane+32).  lane>=32: a'=partner(lane-32), b'=own.
__device__ __forceinline__ void swapl(unsigned& a, unsigned& b) {
  asm("v_permlane32_swap_b32 %0, %1" : "+v"(a), "+v"(b));
}
__device__ __forceinline__ float xmax32(float v) {
  unsigned a = __float_as_uint(v), b = a;
  swapl(a, b);
  return fmaxf(__uint_as_float(a), __uint_as_float(b));
}
__device__ __forceinline__ float xsum32(float v) {
  unsigned a = __float_as_uint(v), b = a;
  swapl(a, b);
  return __uint_as_float(a) + __uint_as_float(b);
}
__device__ __forceinline__ unsigned cvtpk_bf16(float lo, float hi) {
  unsigned r;
  asm("v_cvt_pk_bf16_f32 %0, %1, %2" : "=v"(r) : "v"(lo), "v"(hi));
  return r;
}

// ---------------- weight transpose + f32->bf16 convert ----------------
__global__ __launch_bounds__(256) void k_transpose_cvt(
    const float* __restrict__ W, ushort_t* __restrict__ WT, int K, int N) {
  __shared__ float t[32][33];
  const int tx = threadIdx.x & 31, ty = threadIdx.x >> 5;
  const int n0 = blockIdx.x * 32, k0 = blockIdx.y * 32;
#pragma unroll
  for (int i = 0; i < 4; ++i)
    t[ty + i * 8][tx] = W[(size_t)(k0 + ty + i * 8) * N + n0 + tx];
  __syncthreads();
#pragma unroll
  for (int i = 0; i < 4; ++i)
    WT[(size_t)(n0 + ty + i * 8) * K + k0 + tx] = f2bf(t[tx][ty + i * 8]);
}

// ---------------- layernorm (f32 in -> bf16 out), ddof=1, /(std+eps) ----------------
__global__ __launch_bounds__(256) void k_layernorm(
    const float* __restrict__ x, const float* __restrict__ alpha,
    const float* __restrict__ beta, ushort_t* __restrict__ out) {
  const int row = blockIdx.x;
  const int tid = threadIdx.x;
  const int w = tid >> 6, lane = tid & 63;
  const float4 v = ((const float4*)(x + (size_t)row * Dc))[tid];
  float s = v.x + v.y + v.z + v.w;
#pragma unroll
  for (int m = 32; m >= 1; m >>= 1) s += __shfl_xor(s, m, 64);
  __shared__ float ws[8];
  if (lane == 0) ws[w] = s;
  __syncthreads();
  s = ws[0] + ws[1] + ws[2] + ws[3];
  const float mean = s * (1.0f / Dc);
  const float dx = v.x - mean, dy = v.y - mean, dz = v.z - mean, dw = v.w - mean;
  float ss = dx * dx + dy * dy + dz * dz + dw * dw;
#pragma unroll
  for (int m = 32; m >= 1; m >>= 1) ss += __shfl_xor(ss, m, 64);
  if (lane == 0) ws[4 + w] = ss;
  __syncthreads();
  ss = ws[4] + ws[5] + ws[6] + ws[7];
  const float stdv = sqrtf(ss / (float)(Dc - 1));
  const float inv = 1.0f / (stdv + LN_EPS);
  const float4 a = ((const float4*)alpha)[tid];
  const float4 b = ((const float4*)beta)[tid];
  ushort4 o;
  o.x = f2bf(a.x * dx * inv + b.x);
  o.y = f2bf(a.y * dy * inv + b.y);
  o.z = f2bf(a.z * dz * inv + b.z);
  o.w = f2bf(a.w * dw * inv + b.w);
  *(ushort4*)(out + (size_t)row * Dc + tid * 4) = o;
}

// ---------------- bf16 GEMM, m97 structure ----------------
// MODE 0: bf16 out. 1: f32 out + resid. 2: gelu->bf16. 3: bf16 transposed [B,H,DK,S].
template <int MODE>
__global__ __launch_bounds__(256) void k_gemm(
    const ushort_t* __restrict__ A, const ushort_t* __restrict__ BT,
    const float* __restrict__ bias, const float* __restrict__ resid,
    void* __restrict__ Cout, int N, int K) {
  __shared__ __align__(16) ushort_t As[128 * 32];
  __shared__ __align__(16) ushort_t Bs[128 * 32];
  const int tid = threadIdx.x;
  const int lane = tid & 63;
  const int w = tid >> 6, wm = w >> 1, wn = w & 1;
  const int lrow = lane & 15, lgrp = lane >> 4;
  const int m0 = blockIdx.y << 7, n0 = blockIdx.x << 7;

  const f32x4 zero4 = {0.f, 0.f, 0.f, 0.f};
  f32x4 acc[4][4];
#pragma unroll
  for (int i = 0; i < 4; ++i)
#pragma unroll
    for (int j = 0; j < 4; ++j) acc[i][j] = zero4;

  const int c0 = tid, c1 = tid + 256;
  const ushort_t* Ag0 = A + (size_t)(m0 + (c0 >> 2)) * K + (c0 & 3) * 8;
  const ushort_t* Ag1 = A + (size_t)(m0 + (c1 >> 2)) * K + (c1 & 3) * 8;
  const ushort_t* Bg0 = BT + (size_t)(n0 + (c0 >> 2)) * K + (c0 & 3) * 8;
  const ushort_t* Bg1 = BT + (size_t)(n0 + (c1 >> 2)) * K + (c1 & 3) * 8;
  ushort_t* Al0 = As + c0 * 8;
  ushort_t* Al1 = As + c1 * 8;
  ushort_t* Bl0 = Bs + c0 * 8;
  ushort_t* Bl1 = Bs + c1 * 8;

  int aoff[4], boff[4];
#pragma unroll
  for (int m = 0; m < 4; ++m) aoff[m] = (wm * 64 + m * 16 + lrow) * 32 + lgrp * 8;
#pragma unroll
  for (int n = 0; n < 4; ++n) boff[n] = (wn * 64 + n * 16 + lrow) * 32 + lgrp * 8;

  for (int kk = 0; kk < K; kk += 32) {
    gload_lds16(Ag0 + kk, Al0);
    gload_lds16(Ag1 + kk, Al1);
    gload_lds16(Bg0 + kk, Bl0);
    gload_lds16(Bg1 + kk, Bl1);
    __syncthreads();
    bf16x8 a[4], b[4];
#pragma unroll
    for (int m = 0; m < 4; ++m) a[m] = *(const bf16x8*)(As + aoff[m]);
#pragma unroll
    for (int n = 0; n < 4; ++n) b[n] = *(const bf16x8*)(Bs + boff[n]);
#pragma unroll
    for (int m = 0; m < 4; ++m)
#pragma unroll
      for (int n = 0; n < 4; ++n)
        acc[m][n] = __builtin_amdgcn_mfma_f32_16x16x32_bf16(a[m], b[n], acc[m][n], 0, 0, 0);
    __syncthreads();
  }

  float bv[4];
#pragma unroll
  for (int n = 0; n < 4; ++n) bv[n] = bias[n0 + wn * 64 + n * 16 + lrow];
#pragma unroll
  for (int m = 0; m < 4; ++m)
#pragma unroll
    for (int n = 0; n < 4; ++n) {
      if (MODE == 3) {
        const size_t s0 = (size_t)(m0 + wm * 64 + m * 16 + lgrp * 4);
        const int gb = (int)(s0 >> 11);
        const int ss = (int)(s0 & 2047);
        const int col = n0 + wn * 64 + n * 16 + lrow;
        const int hh = col >> 6, dd = col & 63;
        ushort4 o4;
        o4.x = f2bf(acc[m][n][0] + bv[n]);
        o4.y = f2bf(acc[m][n][1] + bv[n]);
        o4.z = f2bf(acc[m][n][2] + bv[n]);
        o4.w = f2bf(acc[m][n][3] + bv[n]);
        ushort_t* dst = (ushort_t*)Cout + ((size_t)(gb * Hc + hh) * DKc + dd) * Sc + ss;
        *(ushort4*)dst = o4;
      } else {
#pragma unroll
        for (int r = 0; r < 4; ++r) {
          const size_t row = (size_t)(m0 + wm * 64 + m * 16 + lgrp * 4 + r);
          const size_t col = (size_t)(n0 + wn * 64 + n * 16 + lrow);
          float v = acc[m][n][r] + bv[n];
          if (MODE == 2) v = 0.5f * v * (1.0f + erff(v * 0.70710678118654752f));
          if (MODE == 1) {
            v += resid[row * N + col];
            ((float*)Cout)[row * N + col] = v;
          } else {
            ((ushort_t*)Cout)[row * N + col] = f2bf(v);
          }
        }
      }
    }
}

// ---------------- additive mask in log2-exp domain ----------------
__global__ __launch_bounds__(256) void k_maskadd(const int* __restrict__ mask,
                                                float* __restrict__ madd, int n) {
  const int i = blockIdx.x * 256 + threadIdx.x;
  if (i < n) madd[i] = mask[i] ? 0.f : -1.442695041e9f;
}

// ---------------- flash attention v3: swapped QK^T, in-register softmax ----------------
// Q,K: [B,S,H*DK] bf16.  Vt: [B,H,DK,S] bf16.  madd: [B,S] f32.  O: [B,S,H*DK] bf16.
// 4 waves/block, each owns 32 q-rows. No LDS, no barriers.
// Per tile (KVBLK=32): mfma_32x32x16(K,Q) -> lane(q=l31,hi) holds P[kv=(r&3)+8(r>>2)+4hi][q].
#define KSCALE 0.1803368801e0f  /* 0.125 * log2(e) */
#define DEFER_THR 11.5415603f   /* 8 * log2(e) */
__global__ __launch_bounds__(256) void k_attn3(
    const ushort_t* __restrict__ Qb, const ushort_t* __restrict__ Kb,
    const ushort_t* __restrict__ Vt, const float* __restrict__ madd,
    ushort_t* __restrict__ Ob) {
  const int bh = blockIdx.y;
  const int b = bh >> 4, h = bh & 15;
  const int tid = threadIdx.x;
  const int lane = tid & 63, w = tid >> 6;
  const int l31 = lane & 31, hi = lane >> 5;
  const size_t bS = (size_t)b * Sc;
  const int qrow0 = blockIdx.x * 128 + w * 32;

  // Q B-frags: lane(q=l31,hi) holds Q[q][dk=16c+8hi+j]
  bf16x8 qf[4];
  const ushort_t* qp = Qb + (bS + qrow0 + l31) * Dc + h * DKc + hi * 8;
#pragma unroll
  for (int c = 0; c < 4; ++c) qf[c] = *(const bf16x8*)(qp + c * 16);

  f32x16 accA, accB;
#pragma unroll
  for (int i = 0; i < 16; ++i) { accA[i] = 0.f; accB[i] = 0.f; }
  float m2 = -INFINITY, rowl = 0.f;

  const ushort_t* Vth = Vt + (size_t)bh * (DKc * Sc);
  const float* mp = madd + b * Sc;
  const ushort_t* Kbase = Kb + (bS + l31) * Dc + h * DKc + hi * 8;
  const ushort_t* V0 = Vth + (size_t)l31 * Sc + hi * 8;
  const ushort_t* V1 = Vth + (size_t)(32 + l31) * Sc + hi * 8;

  for (int kv = 0; kv < Sc; kv += 32) {
    // QK^T (swapped): A = K rows, B = Q rows -> C[kv][q]
    const ushort_t* kp = Kbase + (size_t)kv * Dc;
    const bf16x8 kf0 = *(const bf16x8*)(kp);
    const bf16x8 kf1 = *(const bf16x8*)(kp + 16);
    const bf16x8 kf2 = *(const bf16x8*)(kp + 32);
    const bf16x8 kf3 = *(const bf16x8*)(kp + 48);
    f32x16 sc;
#pragma unroll
    for (int i = 0; i < 16; ++i) sc[i] = 0.f;
    sc = __builtin_amdgcn_mfma_f32_32x32x16_bf16(kf0, qf[0], sc, 0, 0, 0);
    sc = __builtin_amdgcn_mfma_f32_32x32x16_bf16(kf1, qf[1], sc, 0, 0, 0);
    sc = __builtin_amdgcn_mfma_f32_32x32x16_bf16(kf2, qf[2], sc, 0, 0, 0);
    sc = __builtin_amdgcn_mfma_f32_32x32x16_bf16(kf3, qf[3], sc, 0, 0, 0);
    // masked log2-domain scores: kv_local(r) = (r&3) + 8*(r>>2) + 4*hi
    const float4 ma0 = *(const float4*)(mp + kv + 4 * hi);
    const float4 ma1 = *(const float4*)(mp + kv + 8 + 4 * hi);
    const float4 ma2 = *(const float4*)(mp + kv + 16 + 4 * hi);
    const float4 ma3 = *(const float4*)(mp + kv + 24 + 4 * hi);
    float mv[16];
    mv[0] = ma0.x; mv[1] = ma0.y; mv[2] = ma0.z; mv[3] = ma0.w;
    mv[4] = ma1.x; mv[5] = ma1.y; mv[6] = ma1.z; mv[7] = ma1.w;
    mv[8] = ma2.x; mv[9] = ma2.y; mv[10] = ma2.z; mv[11] = ma2.w;
    mv[12] = ma3.x; mv[13] = ma3.y; mv[14] = ma3.z; mv[15] = ma3.w;
    float p[16];
#pragma unroll
    for (int r = 0; r < 16; ++r) p[r] = sc[r] * KSCALE + mv[r];
    // tile max: in-register tree + one permlane32_swap
    float t[8];
#pragma unroll
    for (int r = 0; r < 8; ++r) t[r] = fmaxf(p[r], p[r + 8]);
#pragma unroll
    for (int r = 0; r < 4; ++r) t[r] = fmaxf(t[r], t[r + 4]);
    const float pmax = xmax32(fmaxf(fmaxf(t[0], t[1]), fmaxf(t[2], t[3])));
    // defer-max: rescale only when tile max grows past threshold (rare)
    if (__any(pmax > m2 + DEFER_THR)) {
      const float mn = fmaxf(m2, pmax);
      const float sq = exp2f(m2 - mn);   // q-layout scale (lane q=l31)
      m2 = mn;
      rowl *= sq;
#pragma unroll
      for (int r = 0; r < 16; ++r) {
        const float s = __shfl(sq, (r & 3) + 8 * (r >> 2) + 4 * hi, 64);
        accA[r] *= s;
        accB[r] *= s;
      }
    }
#pragma unroll
    for (int r = 0; r < 16; ++r) p[r] = exp2f(p[r] - m2);
    float u[8];
#pragma unroll
    for (int r = 0; r < 8; ++r) u[r] = p[r] + p[r + 8];
#pragma unroll
    for (int r = 0; r < 4; ++r) u[r] = u[r] + u[r + 4];
    rowl += xsum32((u[0] + u[1]) + (u[2] + u[3]));
    // P -> bf16 A-frags via cvt_pk + permlane32_swap (no LDS)
    unsigned cw[4][2];
#pragma unroll
    for (int a = 0; a < 4; ++a) {
      cw[a][0] = cvtpk_bf16(p[4 * a + 0], p[4 * a + 1]);
      cw[a][1] = cvtpk_bf16(p[4 * a + 2], p[4 * a + 3]);
    }
    unsigned a00 = cw[0][0], b00 = cw[1][0]; swapl(a00, b00);
    unsigned a01 = cw[0][1], b01 = cw[1][1]; swapl(a01, b01);
    unsigned a10 = cw[2][0], b10 = cw[3][0]; swapl(a10, b10);
    unsigned a11 = cw[2][1], b11 = cw[3][1]; swapl(a11, b11);
    union { unsigned u[4]; bf16x8 v; } pa0, pa1;
    pa0.u[0] = a00; pa0.u[1] = a01; pa0.u[2] = b00; pa0.u[3] = b01;
    pa1.u[0] = a10; pa1.u[1] = a11; pa1.u[2] = b10; pa1.u[3] = b11;
    // PV: B-frags straight from Vt rows (d = h2*32 + l31)
    const bf16x8 v00 = *(const bf16x8*)(V0 + kv);
    const bf16x8 v01 = *(const bf16x8*)(V0 + kv + 16);
    const bf16x8 v10 = *(const bf16x8*)(V1 + kv);
    const bf16x8 v11 = *(const bf16x8*)(V1 + kv + 16);
    accA = __builtin_amdgcn_mfma_f32_32x32x16_bf16(pa0.v, v00, accA, 0, 0, 0);
    accA = __builtin_amdgcn_mfma_f32_32x32x16_bf16(pa1.v, v01, accA, 0, 0, 0);
    accB = __builtin_amdgcn_mfma_f32_32x32x16_bf16(pa0.v, v10, accB, 0, 0, 0);
    accB = __builtin_amdgcn_mfma_f32_32x32x16_bf16(pa1.v, v11, accB, 0, 0, 0);
  }
  // epilogue: O[q][d] = acc / rowl[q]
#pragma unroll
  for (int r = 0; r < 16; ++r) {
    const int q = (r & 3) + 8 * (r >> 2) + 4 * hi;
    const float rl = __shfl(rowl, q, 64);
    const float inv = 1.0f / rl;
    ushort_t* op = Ob + (bS + qrow0 + q) * Dc + h * DKc + l31;
    op[0] = f2bf(accA[r] * inv);
    op[32] = f2bf(accB[r] * inv);
  }
}

// ---------------- launcher ----------------
extern "C" void kernel_launch(void* const* d_in, const int* in_sizes, int n_in,
                              void* d_out, int out_size, void* d_ws, size_t ws_size,
                              hipStream_t stream) {
  const float* x     = (const float*)d_in[0];
  const int* mask    = (const int*)d_in[1];
  const float* wq_w  = (const float*)d_in[2];
  const float* wq_b  = (const float*)d_in[3];
  const float* wk_w  = (const float*)d_in[4];
  const float* wk_b  = (const float*)d_in[5];
  const float* wv_w  = (const float*)d_in[6];
  const float* wv_b  = (const float*)d_in[7];
  const float* wo_w  = (const float*)d_in[8];
  const float* wo_b  = (const float*)d_in[9];
  const float* ff_w0 = (const float*)d_in[10];
  const float* ff_b0 = (const float*)d_in[11];
  const float* ff_w1 = (const float*)d_in[12];
  const float* ff_b1 = (const float*)d_in[13];
  const float* ln0_a = (const float*)d_in[14];
  const float* ln0_b = (const float*)d_in[15];
  const float* ln1_a = (const float*)d_in[16];
  const float* ln1_b = (const float*)d_in[17];
  float* out = (float*)d_out;

  char* ws = (char*)d_ws;
  size_t off = 0;
  ushort_t* WTq = (ushort_t*)(ws + off); off += (size_t)Dc * Dc * 2;
  ushort_t* WTk = (ushort_t*)(ws + off); off += (size_t)Dc * Dc * 2;
  ushort_t* WTv = (ushort_t*)(ws + off); off += (size_t)Dc * Dc * 2;
  ushort_t* WTo = (ushort_t*)(ws + off); off += (size_t)Dc * Dc * 2;
  ushort_t* WT0 = (ushort_t*)(ws + off); off += (size_t)DFFc * Dc * 2;
  ushort_t* WT1 = (ushort_t*)(ws + off); off += (size_t)Dc * DFFc * 2;
  ushort_t* hbuf = (ushort_t*)(ws + off); off += (size_t)Mc * Dc * 2;
  ushort_t* qbuf = (ushort_t*)(ws + off); off += (size_t)Mc * Dc * 2;
  ushort_t* kbuf = (ushort_t*)(ws + off); off += (size_t)Mc * Dc * 2;
  ushort_t* vtb  = (ushort_t*)(ws + off); off += (size_t)Mc * Dc * 2;  // Vt [B,H,DK,S]
  ushort_t* abuf = (ushort_t*)(ws + off); off += (size_t)Mc * Dc * 2;
  float* maddb   = (float*)(ws + off);   off += (size_t)Bc * Sc * 4;
  ushort_t* gbuf = qbuf;  // [8192,4096] overlays dead q/k/vt buffers

  const dim3 blk(256);
  k_transpose_cvt<<<dim3(Dc / 32, Dc / 32), blk, 0, stream>>>(wq_w, WTq, Dc, Dc);
  k_transpose_cvt<<<dim3(Dc / 32, Dc / 32), blk, 0, stream>>>(wk_w, WTk, Dc, Dc);
  k_transpose_cvt<<<dim3(Dc / 32, Dc / 32), blk, 0, stream>>>(wv_w, WTv, Dc, Dc);
  k_transpose_cvt<<<dim3(Dc / 32, Dc / 32), blk, 0, stream>>>(wo_w, WTo, Dc, Dc);
  k_transpose_cvt<<<dim3(DFFc / 32, Dc / 32), blk, 0, stream>>>(ff_w0, WT0, Dc, DFFc);
  k_transpose_cvt<<<dim3(Dc / 32, DFFc / 32), blk, 0, stream>>>(ff_w1, WT1, DFFc, Dc);
  k_maskadd<<<dim3((Bc * Sc + 255) / 256), blk, 0, stream>>>(mask, maddb, Bc * Sc);
  // LN0
  k_layernorm<<<Mc, blk, 0, stream>>>(x, ln0_a, ln0_b, hbuf);
  // Q,K projections; V projection writes pre-transposed [B,H,DK,S]
  k_gemm<0><<<dim3(Dc / 128, Mc / 128), blk, 0, stream>>>(hbuf, WTq, wq_b, nullptr, qbuf, Dc, Dc);
  k_gemm<0><<<dim3(Dc / 128, Mc / 128), blk, 0, stream>>>(hbuf, WTk, wk_b, nullptr, kbuf, Dc, Dc);
  k_gemm<3><<<dim3(Dc / 128, Mc / 128), blk, 0, stream>>>(hbuf, WTv, wv_b, nullptr, vtb, Dc, Dc);
  // attention (swapped-QK^T, in-register softmax)
  k_attn3<<<dim3(Sc / 128, Bc * Hc), blk, 0, stream>>>(qbuf, kbuf, vtb, maddb, abuf);
  // O projection + residual(x) -> d_out (f32)
  k_gemm<1><<<dim3(Dc / 128, Mc / 128), blk, 0, stream>>>(abuf, WTo, wo_b, x, out, Dc, Dc);
  // LN1
  k_layernorm<<<Mc, blk, 0, stream>>>(out, ln1_a, ln1_b, hbuf);
  // FFN0 + exact gelu -> gbuf (bf16)
  k_gemm<2><<<dim3(DFFc / 128, Mc / 128), blk, 0, stream>>>(hbuf, WT0, ff_b0, nullptr, gbuf, DFFc, Dc);
  // FFN1 + residual(d_out) -> d_out (f32)
  k_gemm<1><<<dim3(Dc / 128, Mc / 128), blk, 0, stream>>>(gbuf, WT1, ff_b1, out, out, Dc, DFFc);
}